// Round 2
// baseline (824.798 us; speedup 1.0000x reference)
//
#include <hip/hip_runtime.h>
#include <hip/hip_fp16.h>

// SelfWarp on MI355X, round 2: fp32 inputs/outputs (per reference dtypes),
// fp16 internal precision (MFMA f16; fp16 keeps flow-displacement error
// ~2^-12 relative -> ~0.01 abs output error vs 0.144 threshold).
//   K1 value_kernel: value = u @ w_v^T + b_v            (fp16 MFMA 16x16x32)
//   K2 flow_kernel : flow  = relu(u @ w_f1^T + b_f1) @ w_f2^T + b_f2
//   K3 warp_kernel : periodic bilinear gather of value at base_grid + flow
// ws: [0,134217728) value fp16 (B,128,HW); [+134217728,+67108864) flow packed
// u32 (B,32,HW): lo16 = x-flow fp16, hi16 = y-flow fp16.

typedef unsigned short u16;
typedef unsigned int   u32;
using short8 = __attribute__((ext_vector_type(8))) short;   // 8 fp16 (4 VGPRs)
using f32x4  = __attribute__((ext_vector_type(4))) float;   // MFMA C/D

#define HW     65536
#define NTILES 8192     // 524288 pixels / 64 per tile

__device__ __forceinline__ u16 f2h(float f) {
  return __half_as_ushort(__float2half(f));   // RNE
}
__device__ __forceinline__ float h2f(u16 h) {
  return __half2float(__ushort_as_half(h));
}

// LDS layouts (XOR-swizzled, no padding):
//  - operand rows: row stride 256 B (128 fp16), 16B chunk c of row r stored at
//    chunk index c ^ (r & 15).  Frag reads conflict-free per phase; staging
//    writes <= 2-way (free per m136).
//  - store-staging rows: row stride 128 B (64 fp16), chunk c ^ (r & 7).

// ---------------------------------------------------------------------------
__global__ __launch_bounds__(256) void value_kernel(
    const float* __restrict__ u, const float* __restrict__ wv,
    const float* __restrict__ bv, u16* __restrict__ vout)
{
  __shared__ u16 w_lds[128 * 128];  // w_v [n][k] fp16 swizzled, 32 KB
  __shared__ u16 t_lds[64 * 128];   // u tile [p][k] / value staging [n][m], 16 KB

  const int tid  = threadIdx.x;
  const int lane = tid & 63;
  const int wave = tid >> 6;
  const int m15  = lane & 15;
  const int q    = lane >> 4;

  float vb[8];
#pragma unroll
  for (int nt = 0; nt < 8; ++nt) vb[nt] = bv[nt * 16 + m15];

  {  // stage weights once: fp32 -> fp16, 2048 16B fp16 chunks
    const float4* src = (const float4*)wv;
#pragma unroll
    for (int it = 0; it < 8; ++it) {
      int cid = it * 256 + tid;
      int n = cid >> 4, kc = cid & 15;
      float4 a = src[cid * 2 + 0];
      float4 c = src[cid * 2 + 1];
      uint4 pk;
      pk.x = (u32)f2h(a.x) | ((u32)f2h(a.y) << 16);
      pk.y = (u32)f2h(a.z) | ((u32)f2h(a.w) << 16);
      pk.z = (u32)f2h(c.x) | ((u32)f2h(c.y) << 16);
      pk.w = (u32)f2h(c.z) | ((u32)f2h(c.w) << 16);
      *(uint4*)((char*)w_lds + n * 256 + ((kc ^ (n & 15)) << 4)) = pk;
    }
  }
  __syncthreads();

  for (int tile = blockIdx.x; tile < NTILES; tile += (int)gridDim.x) {
    const int gbase = tile << 6;          // global pixel
    const int b     = gbase >> 16;        // tiles never cross batch (HW%64==0)
    const int img   = gbase & 65535;
    const float* ub = u + ((size_t)b << 23) + img;  // + c*HW + p

    {  // stage u tile: 8 channels of one pixel -> one b128 write, cvt fp16
      const int p  = tid & 63;
      const int cb = (tid >> 6) << 3;
#pragma unroll
      for (int pass = 0; pass < 4; ++pass) {
        int c0 = cb + pass * 32;
        float v0 = ub[(size_t)(c0 + 0) * HW + p];
        float v1 = ub[(size_t)(c0 + 1) * HW + p];
        float v2 = ub[(size_t)(c0 + 2) * HW + p];
        float v3 = ub[(size_t)(c0 + 3) * HW + p];
        float v4 = ub[(size_t)(c0 + 4) * HW + p];
        float v5 = ub[(size_t)(c0 + 5) * HW + p];
        float v6 = ub[(size_t)(c0 + 6) * HW + p];
        float v7 = ub[(size_t)(c0 + 7) * HW + p];
        uint4 pk;
        pk.x = (u32)f2h(v0) | ((u32)f2h(v1) << 16);
        pk.y = (u32)f2h(v2) | ((u32)f2h(v3) << 16);
        pk.z = (u32)f2h(v4) | ((u32)f2h(v5) << 16);
        pk.w = (u32)f2h(v6) | ((u32)f2h(v7) << 16);
        *(uint4*)((char*)t_lds + p * 256 + (((c0 >> 3) ^ (p & 15)) << 4)) = pk;
      }
    }
    __syncthreads();

    f32x4 zero = {0.f, 0.f, 0.f, 0.f};
    f32x4 acc[8];
#pragma unroll
    for (int nt = 0; nt < 8; ++nt) acc[nt] = zero;

    const int arow = wave * 16 + m15;     // A: m = lane&15
#pragma unroll
    for (int kc = 0; kc < 4; ++kc) {
      short8 af = *(const short8*)((const char*)t_lds + arow * 256 +
                                   ((((kc << 2) + q) ^ (arow & 15)) << 4));
#pragma unroll
      for (int nt = 0; nt < 8; ++nt) {
        int brow = nt * 16 + m15;         // B: n = lane&15
        short8 bf = *(const short8*)((const char*)w_lds + brow * 256 +
                                     ((((kc << 2) + q) ^ (brow & 15)) << 4));
        acc[nt] = __builtin_amdgcn_mfma_f32_16x16x32_f16(af, bf, acc[nt], 0, 0, 0);
      }
    }
    __syncthreads();  // all u reads done; reuse t_lds as [n 128][m 64] staging

#pragma unroll
    for (int nt = 0; nt < 8; ++nt) {
      int n = nt * 16 + m15;              // C/D: col = lane&15
#pragma unroll
      for (int r = 0; r < 4; ++r) {
        int m = wave * 16 + q * 4 + r;    // C/D: row = quad*4 + reg
        *(u16*)((char*)t_lds + n * 128 + (((m >> 3) ^ (n & 7)) << 4) +
                ((m & 7) << 1)) = f2h(acc[nt][r] + vb[nt]);
      }
    }
    __syncthreads();

#pragma unroll
    for (int pass = 0; pass < 8; ++pass) {  // coalesced fp16 store, 4 pix/thread
      int ch = (tid >> 4) + (pass << 4);
      int p4 = (tid & 15) << 2;
      uint2 dd = *(const uint2*)((const char*)t_lds + ch * 128 +
                                 (((p4 >> 3) ^ (ch & 7)) << 4) + ((p4 & 4) << 1));
      *(uint2*)(vout + (((size_t)(b * 128 + ch)) << 16) + img + p4) = dd;
    }
    __syncthreads();  // before next tile overwrites t_lds
  }
}

// ---------------------------------------------------------------------------
__global__ __launch_bounds__(256) void flow_kernel(
    const float* __restrict__ u,  const float* __restrict__ w1,
    const float* __restrict__ b1, const float* __restrict__ w2,
    const float* __restrict__ b2, u32* __restrict__ fout)
{
  __shared__ u16 w1_lds[128 * 128];  // 32 KB
  __shared__ u16 w2_lds[64 * 128];   // 16 KB
  __shared__ u16 t_lds[64 * 128];    // 16 KB: u tile -> hmid tile -> flow staging

  const int tid  = threadIdx.x;
  const int lane = tid & 63;
  const int wave = tid >> 6;
  const int m15  = lane & 15;
  const int q    = lane >> 4;

  float hb[8], fb[4];
#pragma unroll
  for (int nt = 0; nt < 8; ++nt) hb[nt] = b1[nt * 16 + m15];
#pragma unroll
  for (int nt = 0; nt < 4; ++nt) fb[nt] = b2[nt * 16 + m15];

  {
    const float4* s1 = (const float4*)w1;
#pragma unroll
    for (int it = 0; it < 8; ++it) {
      int cid = it * 256 + tid;
      int n = cid >> 4, kc = cid & 15;
      float4 a = s1[cid * 2 + 0];
      float4 c = s1[cid * 2 + 1];
      uint4 pk;
      pk.x = (u32)f2h(a.x) | ((u32)f2h(a.y) << 16);
      pk.y = (u32)f2h(a.z) | ((u32)f2h(a.w) << 16);
      pk.z = (u32)f2h(c.x) | ((u32)f2h(c.y) << 16);
      pk.w = (u32)f2h(c.z) | ((u32)f2h(c.w) << 16);
      *(uint4*)((char*)w1_lds + n * 256 + ((kc ^ (n & 15)) << 4)) = pk;
    }
    const float4* s2 = (const float4*)w2;
#pragma unroll
    for (int it = 0; it < 4; ++it) {
      int cid = it * 256 + tid;
      int n = cid >> 4, kc = cid & 15;
      float4 a = s2[cid * 2 + 0];
      float4 c = s2[cid * 2 + 1];
      uint4 pk;
      pk.x = (u32)f2h(a.x) | ((u32)f2h(a.y) << 16);
      pk.y = (u32)f2h(a.z) | ((u32)f2h(a.w) << 16);
      pk.z = (u32)f2h(c.x) | ((u32)f2h(c.y) << 16);
      pk.w = (u32)f2h(c.z) | ((u32)f2h(c.w) << 16);
      *(uint4*)((char*)w2_lds + n * 256 + ((kc ^ (n & 15)) << 4)) = pk;
    }
  }
  __syncthreads();

  for (int tile = blockIdx.x; tile < NTILES; tile += (int)gridDim.x) {
    const int gbase = tile << 6;
    const int b     = gbase >> 16;
    const int img   = gbase & 65535;
    const float* ub = u + ((size_t)b << 23) + img;

    {
      const int p  = tid & 63;
      const int cb = (tid >> 6) << 3;
#pragma unroll
      for (int pass = 0; pass < 4; ++pass) {
        int c0 = cb + pass * 32;
        float v0 = ub[(size_t)(c0 + 0) * HW + p];
        float v1 = ub[(size_t)(c0 + 1) * HW + p];
        float v2 = ub[(size_t)(c0 + 2) * HW + p];
        float v3 = ub[(size_t)(c0 + 3) * HW + p];
        float v4 = ub[(size_t)(c0 + 4) * HW + p];
        float v5 = ub[(size_t)(c0 + 5) * HW + p];
        float v6 = ub[(size_t)(c0 + 6) * HW + p];
        float v7 = ub[(size_t)(c0 + 7) * HW + p];
        uint4 pk;
        pk.x = (u32)f2h(v0) | ((u32)f2h(v1) << 16);
        pk.y = (u32)f2h(v2) | ((u32)f2h(v3) << 16);
        pk.z = (u32)f2h(v4) | ((u32)f2h(v5) << 16);
        pk.w = (u32)f2h(v6) | ((u32)f2h(v7) << 16);
        *(uint4*)((char*)t_lds + p * 256 + (((c0 >> 3) ^ (p & 15)) << 4)) = pk;
      }
    }
    __syncthreads();

    f32x4 zero = {0.f, 0.f, 0.f, 0.f};
    f32x4 hm[8];
#pragma unroll
    for (int nt = 0; nt < 8; ++nt) hm[nt] = zero;

    const int arow = wave * 16 + m15;
#pragma unroll
    for (int kc = 0; kc < 4; ++kc) {
      short8 af = *(const short8*)((const char*)t_lds + arow * 256 +
                                   ((((kc << 2) + q) ^ (arow & 15)) << 4));
#pragma unroll
      for (int nt = 0; nt < 8; ++nt) {
        int brow = nt * 16 + m15;
        short8 bf = *(const short8*)((const char*)w1_lds + brow * 256 +
                                     ((((kc << 2) + q) ^ (brow & 15)) << 4));
        hm[nt] = __builtin_amdgcn_mfma_f32_16x16x32_f16(af, bf, hm[nt], 0, 0, 0);
      }
    }
    __syncthreads();  // u reads done; overwrite t_lds with hmid in A-layout

#pragma unroll
    for (int nt = 0; nt < 8; ++nt) {
      int k = nt * 16 + m15;              // hmid channel
#pragma unroll
      for (int r = 0; r < 4; ++r) {
        int m = wave * 16 + q * 4 + r;    // pixel row
        float h = fmaxf(hm[nt][r] + hb[nt], 0.f);
        *(u16*)((char*)t_lds + m * 256 + (((k >> 3) ^ (m & 15)) << 4) +
                ((k & 7) << 1)) = f2h(h);
      }
    }
    __syncthreads();

    f32x4 fl[4];
#pragma unroll
    for (int nt = 0; nt < 4; ++nt) fl[nt] = zero;
#pragma unroll
    for (int kc = 0; kc < 4; ++kc) {
      short8 af = *(const short8*)((const char*)t_lds + arow * 256 +
                                   ((((kc << 2) + q) ^ (arow & 15)) << 4));
#pragma unroll
      for (int nt = 0; nt < 4; ++nt) {
        int brow = nt * 16 + m15;
        short8 bf = *(const short8*)((const char*)w2_lds + brow * 256 +
                                     ((((kc << 2) + q) ^ (brow & 15)) << 4));
        fl[nt] = __builtin_amdgcn_mfma_f32_16x16x32_f16(af, bf, fl[nt], 0, 0, 0);
      }
    }
    __syncthreads();  // hmid reads done; reuse t_lds as [ch 64][m 64] staging

#pragma unroll
    for (int nt = 0; nt < 4; ++nt) {
      int n = nt * 16 + m15;              // flow channel = head*2 + dir
#pragma unroll
      for (int r = 0; r < 4; ++r) {
        int m = wave * 16 + q * 4 + r;
        *(u16*)((char*)t_lds + n * 128 + (((m >> 3) ^ (n & 7)) << 4) +
                ((m & 7) << 1)) = f2h(fl[nt][r] + fb[nt]);
      }
    }
    __syncthreads();

#pragma unroll
    for (int pass = 0; pass < 2; ++pass) {  // interleave (x,y) -> packed dword/pixel
      int h  = (tid >> 4) + (pass << 4);
      int p4 = (tid & 15) << 2;
      int c0 = 2 * h, c1 = 2 * h + 1;
      uint2 xx = *(const uint2*)((const char*)t_lds + c0 * 128 +
                                 (((p4 >> 3) ^ (c0 & 7)) << 4) + ((p4 & 4) << 1));
      uint2 yy = *(const uint2*)((const char*)t_lds + c1 * 128 +
                                 (((p4 >> 3) ^ (c1 & 7)) << 4) + ((p4 & 4) << 1));
      uint4 o;
      o.x = (xx.x & 0xffffu) | (yy.x << 16);
      o.y = (xx.x >> 16)     | (yy.x & 0xffff0000u);
      o.z = (xx.y & 0xffffu) | (yy.y << 16);
      o.w = (xx.y >> 16)     | (yy.y & 0xffff0000u);
      *(uint4*)(fout + (((size_t)(b * 32 + h)) << 16) + img + p4) = o;
    }
    __syncthreads();
  }
}

// ---------------------------------------------------------------------------
__global__ __launch_bounds__(256) void warp_kernel(
    const u16* __restrict__ value, const u32* __restrict__ flow,
    float* __restrict__ out)
{
  const int gt  = blockIdx.x * 256 + threadIdx.x;  // (b*32+head)*HW + pix
  const int pix = gt & 65535;
  const int hb  = gt >> 16;                        // b*32 + head

  u32 f    = flow[gt];
  float fx = h2f((u16)(f & 0xffffu));
  float fy = h2f((u16)(f >> 16));

  const int wq = pix & 255, hq = pix >> 8;
  // base grid: linspace(-1,1,256) -> -1 + 2*i/255, then unnormalize + wrap
  float gx = -1.f + (2.f / 255.f) * (float)wq + fx;
  float gy = -1.f + (2.f / 255.f) * (float)hq + fy;
  float pxr = ((gx + 1.f) * 256.f - 1.f) * 0.5f;
  float pyr = ((gy + 1.f) * 256.f - 1.f) * 0.5f;
  float px = pxr - floorf(pxr * (1.f / 256.f)) * 256.f;
  float py = pyr - floorf(pyr * (1.f / 256.f)) * 256.f;
  if (px >= 256.f) px -= 256.f;   // rounding guard
  if (py >= 256.f) py -= 256.f;
  if (px < 0.f) px = 0.f;
  if (py < 0.f) py = 0.f;

  float x0f = floorf(px), y0f = floorf(py);
  float wx = px - x0f, wy = py - y0f;
  int x0 = (int)x0f; if (x0 > 255) x0 = 255;
  int y0 = (int)y0f; if (y0 > 255) y0 = 255;
  int x1 = (x0 + 1) & 255;
  int y1 = (y0 + 1) & 255;

  float w00 = (1.f - wx) * (1.f - wy);
  float w01 = wx * (1.f - wy);
  float w10 = (1.f - wx) * wy;
  float w11 = wx * wy;

  int i00 = y0 * 256 + x0, i01 = y0 * 256 + x1;
  int i10 = y1 * 256 + x0, i11 = y1 * 256 + x1;

  const u16* vb = value + ((size_t)hb << 18);  // (b*128 + head*4) * HW
  float* ob = out + ((size_t)hb << 18) + pix;
#pragma unroll
  for (int ci = 0; ci < 4; ++ci) {
    const u16* vr = vb + ((size_t)ci << 16);
    float v00 = h2f(vr[i00]), v01 = h2f(vr[i01]);
    float v10 = h2f(vr[i10]), v11 = h2f(vr[i11]);
    ob[(size_t)ci << 16] = w00 * v00 + w01 * v01 + w10 * v10 + w11 * v11;
  }
}

// ---------------------------------------------------------------------------
extern "C" void kernel_launch(void* const* d_in, const int* in_sizes, int n_in,
                              void* d_out, int out_size, void* d_ws, size_t ws_size,
                              hipStream_t stream) {
  const float* u  = (const float*)d_in[0];
  const float* w1 = (const float*)d_in[1];
  const float* b1 = (const float*)d_in[2];
  const float* w2 = (const float*)d_in[3];
  const float* b2 = (const float*)d_in[4];
  const float* wv = (const float*)d_in[5];
  const float* bv = (const float*)d_in[6];

  u16* value_ws = (u16*)d_ws;                        // 134,217,728 B
  u32* flow_ws  = (u32*)((char*)d_ws + 134217728);   //  67,108,864 B
  float* out    = (float*)d_out;

  value_kernel<<<dim3(1024), dim3(256), 0, stream>>>(u, wv, bv, value_ws);
  flow_kernel<<<dim3(512),  dim3(256), 0, stream>>>(u, w1, b1, w2, b2, flow_ws);
  warp_kernel<<<dim3(65536), dim3(256), 0, stream>>>(value_ws, flow_ws, out);
}